// Round 6
// baseline (310.963 us; speedup 1.0000x reference)
//
#include <hip/hip_runtime.h>

// GCN VGAE encoder, pull-based. N=50000 (<2^16: rows pack in 16 bits), E=1.6M.
// out[i] = dis[i] * (hs[i] + sum_{j->i} hs[j]),  hs = dis .* (x@W)
// CSR build: coarse-bucket (256 nodes) counting sort with XCD-clean writes.

#define NBMAX 256

__device__ __forceinline__ float4 f4add(float4 a, float4 b) {
    return make_float4(a.x + b.x, a.y + b.y, a.z + b.z, a.w + b.w);
}

__global__ __launch_bounds__(256) void k_hist(const int* __restrict__ col,
                                              int* __restrict__ bcnt, int e) {
    __shared__ int h[NBMAX];
    for (int i = threadIdx.x; i < NBMAX; i += 256) h[i] = 0;
    __syncthreads();
    for (int i = blockIdx.x * 256 + threadIdx.x; i < e; i += gridDim.x * 256)
        atomicAdd(&h[col[i] >> 8], 1);
    __syncthreads();
    for (int i = threadIdx.x; i < NBMAX; i += 256)
        if (h[i]) atomicAdd(bcnt + i, h[i]);
}

__global__ __launch_bounds__(256) void k_scanb(const int* __restrict__ bcnt,
                                               int* __restrict__ bbase,
                                               int* __restrict__ bcur,
                                               int* __restrict__ rowptr,
                                               int nb, int n, int e) {
    __shared__ int s[256];
    int t = threadIdx.x;
    int v = (t < nb) ? bcnt[t] : 0;
    s[t] = v;
    __syncthreads();
    for (int off = 1; off < 256; off <<= 1) {
        int u = (t >= off) ? s[t - off] : 0;
        __syncthreads();
        s[t] += u;
        __syncthreads();
    }
    int excl = s[t] - v;
    if (t <= nb) bbase[t] = (t < nb) ? excl : e;
    if (t < nb) bcur[t] = excl;
    if (t == 0) rowptr[n] = e;
}

__global__ __launch_bounds__(256) void k_tilesort(const int* __restrict__ row,
                                                  const int* __restrict__ col,
                                                  int* __restrict__ bcur,
                                                  int* __restrict__ binbuf,
                                                  int e, int chunk) {
    __shared__ int lh[NBMAX];
    int t0 = blockIdx.x * chunk;
    int t1 = t0 + chunk < e ? t0 + chunk : e;
    for (int i = threadIdx.x; i < NBMAX; i += 256) lh[i] = 0;
    __syncthreads();
    for (int i = t0 + threadIdx.x; i < t1; i += 256)
        atomicAdd(&lh[col[i] >> 8], 1);
    __syncthreads();
    for (int b = threadIdx.x; b < NBMAX; b += 256) {
        int c = lh[b];
        if (c) lh[b] = atomicAdd(bcur + b, c);
    }
    __syncthreads();
    for (int i = t0 + threadIdx.x; i < t1; i += 256) {
        int c = col[i];
        int pos = atomicAdd(&lh[c >> 8], 1);
        binbuf[pos] = row[i] | ((c & 255) << 16);
    }
}

__global__ __launch_bounds__(256) void k_build(const int* __restrict__ binbuf,
                                               const int* __restrict__ bbase,
                                               float* __restrict__ dis,
                                               int* __restrict__ rowptr,
                                               int* __restrict__ csr, int n) {
    __shared__ int lcnt[256], s[256], cur[256];
    int b = blockIdx.x;
    int t = threadIdx.x;
    int lo = bbase[b], hi = bbase[b + 1];
    int node0 = b << 8;
    int nloc = n - node0 < 256 ? n - node0 : 256;
    lcnt[t] = 0;
    __syncthreads();
    for (int k = lo + t; k < hi; k += 256)
        atomicAdd(&lcnt[(binbuf[k] >> 16) & 255], 1);
    __syncthreads();
    int v = lcnt[t];
    s[t] = v;
    __syncthreads();
    for (int off = 1; off < 256; off <<= 1) {
        int u = (t >= off) ? s[t - off] : 0;
        __syncthreads();
        s[t] += u;
        __syncthreads();
    }
    if (t < nloc) {
        int rp = lo + s[t] - v;
        rowptr[node0 + t] = rp;
        cur[t] = rp;
        dis[node0 + t] = rsqrtf((float)v + 1.0f);
    }
    __syncthreads();
    for (int k = lo + t; k < hi; k += 256) {
        int p = binbuf[k];
        int pos = atomicAdd(&cur[(p >> 16) & 255], 1);
        csr[pos] = p & 0xffff;
    }
}

// x[n,128] @ W[128,64] * dis -> hs1[n,64]. 64 rows/block, 16 rows/wave in regs.
// W staged transposed in LDS as float4 w4[c][k4], padded stride 33.
__global__ __launch_bounds__(256) void k_gemm1(const float* __restrict__ x,
                                               const float* __restrict__ W,
                                               const float* __restrict__ dis,
                                               float* __restrict__ hs1, int n) {
    __shared__ float w4[64 * 33 * 4];
    for (int i = threadIdx.x; i < 128 * 64; i += 256) {
        int k = i >> 6, c = i & 63;
        w4[(c * 33 + (k >> 2)) * 4 + (k & 3)] = W[i];
    }
    __syncthreads();
    int wid = threadIdx.x >> 6;
    int ch = threadIdx.x & 63;
    int r0 = blockIdx.x * 64 + wid * 16;
    float acc[16];
#pragma unroll
    for (int r = 0; r < 16; ++r) acc[r] = 0.f;
    const float4* x4 = (const float4*)x;
    const float4* wl = (const float4*)w4;
    if (r0 + 16 <= n) {
        const float4* xb = x4 + (size_t)r0 * 32;
#pragma unroll 2
        for (int k4 = 0; k4 < 32; ++k4) {
            float4 wv = wl[ch * 33 + k4];
#pragma unroll
            for (int r = 0; r < 16; ++r) {
                float4 xv = xb[r * 32 + k4];
                acc[r] = fmaf(xv.x, wv.x, acc[r]);
                acc[r] = fmaf(xv.y, wv.y, acc[r]);
                acc[r] = fmaf(xv.z, wv.z, acc[r]);
                acc[r] = fmaf(xv.w, wv.w, acc[r]);
            }
        }
#pragma unroll
        for (int r = 0; r < 16; ++r)
            hs1[(size_t)(r0 + r) * 64 + ch] = dis[r0 + r] * acc[r];
    } else {
#pragma unroll 2
        for (int k4 = 0; k4 < 32; ++k4) {
            float4 wv = wl[ch * 33 + k4];
#pragma unroll
            for (int r = 0; r < 16; ++r) {
                int rr = r0 + r < n ? r0 + r : n - 1;
                float4 xv = x4[(size_t)rr * 32 + k4];
                acc[r] = fmaf(xv.x, wv.x, acc[r]);
                acc[r] = fmaf(xv.y, wv.y, acc[r]);
                acc[r] = fmaf(xv.z, wv.z, acc[r]);
                acc[r] = fmaf(xv.w, wv.w, acc[r]);
            }
        }
#pragma unroll
        for (int r = 0; r < 16; ++r)
            if (r0 + r < n) hs1[(size_t)(r0 + r) * 64 + ch] = dis[r0 + r] * acc[r];
    }
}

// pull + relu: hs2[i] = dis[i]*relu(dis[i]*(hs1[i]+sum_neigh)+b1)
// 16 lanes per node, float4 channels.
__global__ __launch_bounds__(256) void k_pull1(const int* __restrict__ rowptr,
                                               const int* __restrict__ csr,
                                               const float* __restrict__ hs1,
                                               const float* __restrict__ dis,
                                               const float* __restrict__ b1,
                                               float* __restrict__ hs2, int n) {
    int node = blockIdx.x * 16 + (threadIdx.x >> 4);
    int c4 = threadIdx.x & 15;
    if (node >= n) return;
    const float4* h4 = (const float4*)hs1;
    int beg = rowptr[node], end = rowptr[node + 1];
    float4 a0 = h4[(size_t)node * 16 + c4];
    float4 a1 = make_float4(0, 0, 0, 0), a2 = a1, a3 = a1;
    int k = beg;
    for (; k + 4 <= end; k += 4) {
        int s0 = csr[k], s1 = csr[k + 1], s2 = csr[k + 2], s3 = csr[k + 3];
        a0 = f4add(a0, h4[(size_t)s0 * 16 + c4]);
        a1 = f4add(a1, h4[(size_t)s1 * 16 + c4]);
        a2 = f4add(a2, h4[(size_t)s2 * 16 + c4]);
        a3 = f4add(a3, h4[(size_t)s3 * 16 + c4]);
    }
    for (; k < end; ++k) a0 = f4add(a0, h4[(size_t)csr[k] * 16 + c4]);
    float4 sum = f4add(f4add(a0, a1), f4add(a2, a3));
    float d = dis[node];
    float4 bb = ((const float4*)b1)[c4];
    float4 o;
    o.x = fmaf(d, sum.x, bb.x); o.x = o.x > 0.f ? d * o.x : 0.f;
    o.y = fmaf(d, sum.y, bb.y); o.y = o.y > 0.f ? d * o.y : 0.f;
    o.z = fmaf(d, sum.z, bb.z); o.z = o.z > 0.f ? d * o.z : 0.f;
    o.w = fmaf(d, sum.w, bb.w); o.w = o.w > 0.f ? d * o.w : 0.f;
    ((float4*)hs2)[(size_t)node * 16 + c4] = o;
}

// pull: gagg[i] = dis[i]*(hs2[i]+sum_neigh)
__global__ __launch_bounds__(256) void k_pull2(const int* __restrict__ rowptr,
                                               const int* __restrict__ csr,
                                               const float* __restrict__ hs2,
                                               const float* __restrict__ dis,
                                               float* __restrict__ gagg, int n) {
    int node = blockIdx.x * 16 + (threadIdx.x >> 4);
    int c4 = threadIdx.x & 15;
    if (node >= n) return;
    const float4* h4 = (const float4*)hs2;
    int beg = rowptr[node], end = rowptr[node + 1];
    float4 a0 = h4[(size_t)node * 16 + c4];
    float4 a1 = make_float4(0, 0, 0, 0), a2 = a1, a3 = a1;
    int k = beg;
    for (; k + 4 <= end; k += 4) {
        int s0 = csr[k], s1 = csr[k + 1], s2 = csr[k + 2], s3 = csr[k + 3];
        a0 = f4add(a0, h4[(size_t)s0 * 16 + c4]);
        a1 = f4add(a1, h4[(size_t)s1 * 16 + c4]);
        a2 = f4add(a2, h4[(size_t)s2 * 16 + c4]);
        a3 = f4add(a3, h4[(size_t)s3 * 16 + c4]);
    }
    for (; k < end; ++k) a0 = f4add(a0, h4[(size_t)csr[k] * 16 + c4]);
    float4 sum = f4add(f4add(a0, a1), f4add(a2, a3));
    float d = dis[node];
    float4 o = make_float4(d * sum.x, d * sum.y, d * sum.z, d * sum.w);
    ((float4*)gagg)[(size_t)node * 16 + c4] = o;
}

// g[n,64] @ {W2,W3}[64,32] + bias -> out = mu ++ logvar.
// 128 rows/block; each 32-lane half-wave holds 16 rows in regs.
__global__ __launch_bounds__(256) void k_gemm23(const float* __restrict__ g,
                                                const float* __restrict__ W2,
                                                const float* __restrict__ b2,
                                                const float* __restrict__ W3,
                                                const float* __restrict__ b3,
                                                float* __restrict__ out, int n) {
    __shared__ float w2s[32 * 17 * 4], w3s[32 * 17 * 4];
    for (int i = threadIdx.x; i < 64 * 32; i += 256) {
        int k = i >> 5, c = i & 31;
        int a = (c * 17 + (k >> 2)) * 4 + (k & 3);
        w2s[a] = W2[i];
        w3s[a] = W3[i];
    }
    __syncthreads();
    int ch = threadIdx.x & 31;
    int half = (threadIdx.x >> 5) & 1;
    int wid = threadIdx.x >> 6;
    int r0 = blockIdx.x * 128 + wid * 32 + half * 16;
    float acc2[16], acc3[16];
#pragma unroll
    for (int r = 0; r < 16; ++r) { acc2[r] = 0.f; acc3[r] = 0.f; }
    const float4* g4 = (const float4*)g;
    const float4* w2l = (const float4*)w2s;
    const float4* w3l = (const float4*)w3s;
#pragma unroll 2
    for (int k4 = 0; k4 < 16; ++k4) {
        float4 wv2 = w2l[ch * 17 + k4];
        float4 wv3 = w3l[ch * 17 + k4];
#pragma unroll
        for (int r = 0; r < 16; ++r) {
            int rr = r0 + r < n ? r0 + r : n - 1;
            float4 gv = g4[(size_t)rr * 16 + k4];
            acc2[r] = fmaf(gv.x, wv2.x, acc2[r]);
            acc2[r] = fmaf(gv.y, wv2.y, acc2[r]);
            acc2[r] = fmaf(gv.z, wv2.z, acc2[r]);
            acc2[r] = fmaf(gv.w, wv2.w, acc2[r]);
            acc3[r] = fmaf(gv.x, wv3.x, acc3[r]);
            acc3[r] = fmaf(gv.y, wv3.y, acc3[r]);
            acc3[r] = fmaf(gv.z, wv3.z, acc3[r]);
            acc3[r] = fmaf(gv.w, wv3.w, acc3[r]);
        }
    }
    float bb2 = b2[ch], bb3 = b3[ch];
#pragma unroll
    for (int r = 0; r < 16; ++r) {
        int row = r0 + r;
        if (row < n) {
            out[(size_t)row * 32 + ch] = acc2[r] + bb2;
            out[(size_t)n * 32 + (size_t)row * 32 + ch] = acc3[r] + bb3;
        }
    }
}

extern "C" void kernel_launch(void* const* d_in, const int* in_sizes, int n_in,
                              void* d_out, int out_size, void* d_ws, size_t ws_size,
                              hipStream_t stream) {
    const float* x  = (const float*)d_in[0];
    const int*   ei = (const int*)d_in[1];
    const float* W1 = (const float*)d_in[2];
    const float* b1 = (const float*)d_in[3];
    const float* W2 = (const float*)d_in[4];
    const float* b2 = (const float*)d_in[5];
    const float* W3 = (const float*)d_in[6];
    const float* b3 = (const float*)d_in[7];

    int n = in_sizes[0] / 128;   // 50000
    int e = in_sizes[1] / 2;     // 1600000
    int nb = (n + 255) >> 8;     // 196 coarse buckets
    const int* row = ei;
    const int* col = ei + e;

    float* fws  = (float*)d_ws;
    float* dis  = fws;                        // n
    float* hs1  = fws + n;                    // n*64 (16B-aligned: n%4==0)
    float* hs2  = hs1 + (size_t)n * 64;       // n*64
    float* gagg = hs1;                        // alias: hs1 dead after pull1
    int* binbuf = (int*)hs1;                  // e ints, dead before gemm1
    int* cnt    = (int*)(hs2 + (size_t)n * 64);
    int* bbase  = cnt + nb;
    int* bcur   = bbase + nb + 1;
    int* rowptr = bcur + nb;
    int* csr    = rowptr + n + 1;
    float* out  = (float*)d_out;

    int chunk = (e + nb - 1) / nb;

    dim3 blk(256);
    hipMemsetAsync(cnt, 0, (size_t)nb * 4, stream);
    k_hist<<<nb, blk, 0, stream>>>(col, cnt, e);
    k_scanb<<<1, blk, 0, stream>>>(cnt, bbase, bcur, rowptr, nb, n, e);
    k_tilesort<<<nb, blk, 0, stream>>>(row, col, bcur, binbuf, e, chunk);
    k_build<<<nb, blk, 0, stream>>>(binbuf, bbase, dis, rowptr, csr, n);

    k_gemm1<<<(n + 63) / 64, blk, 0, stream>>>(x, W1, dis, hs1, n);
    k_pull1<<<(n + 15) / 16, blk, 0, stream>>>(rowptr, csr, hs1, dis, b1, hs2, n);
    k_pull2<<<(n + 15) / 16, blk, 0, stream>>>(rowptr, csr, hs2, dis, gagg, n);
    k_gemm23<<<(n + 127) / 128, blk, 0, stream>>>(gagg, W2, b2, W3, b3, out, n);
}